// Round 1
// baseline (167.322 us; speedup 1.0000x reference)
//
#include <hip/hip_runtime.h>
#include <math.h>

#define N_NODES  100000
#define N_PATHS  1000000
#define E_TOT    8000000
#define NW_TOT   (E_TOT / 4)    // r8 words
#define NF       9              // rfft bins for n=16
#define TAB_U32  25000          // 100000 bytes as u32
#define EB       1024           // epass threads
#define EPT      8              // int4 groups per epass thread (245 blocks = 1/CU)
#define PB       256            // path_kernel threads
#define KW       9              // preloaded r8 words per path: covers len <= 32

// r quantization range: r = exp(-1/(p+0.5)), p in [0,1)
#define RMIN 0.135330f
#define RMAX 0.513420f
#define QSCALE (255.0f / (RMAX - RMIN))
#define DEQ    ((RMAX - RMIN) / 255.0f)

typedef int   v4i __attribute__((ext_vector_type(4)));
typedef float v4f __attribute__((ext_vector_type(4)));

// cos/sin(2*pi*k/16)
__device__ __constant__ float COS16[16] = {
  1.0f,  0.92387953f,  0.70710678f,  0.38268343f,  0.0f, -0.38268343f, -0.70710678f, -0.92387953f,
 -1.0f, -0.92387953f, -0.70710678f, -0.38268343f,  0.0f,  0.38268343f,  0.70710678f,  0.92387953f };
__device__ __constant__ float SIN16[16] = {
  0.0f,  0.38268343f,  0.70710678f,  0.92387953f,  1.0f,  0.92387953f,  0.70710678f,  0.38268343f,
  0.0f, -0.38268343f, -0.70710678f, -0.92387953f, -1.0f, -0.92387953f, -0.70710678f, -0.38268343f };

// Stage 1: quantized node table. r[n] = exp(-1/(params[n]+0.5)) -> u8.
// rfft16 of x[t]=r^t/k is A/(1 - r e^{-i w_f}); positive real A cancels
// under relu+normalize, so r alone captures the node.
__global__ void node_rq_kernel(const float* __restrict__ params,
                               unsigned char* __restrict__ rtab_q) {
    int n = blockIdx.x * blockDim.x + threadIdx.x;
    if (n >= N_NODES) return;
    float k = params[n] + 0.5f;
    float r = expf(-1.0f / k);
    float q = (r - RMIN) * QSCALE;
    q = fminf(fmaxf(q + 0.5f, 0.0f), 255.0f);
    rtab_q[n] = (unsigned char)q;
}

__device__ __forceinline__ void put_bounds(int a, int b, int e, int* __restrict__ start) {
    for (int p = a + 1; p <= b; ++p) start[p] = e;
}

// Stage 2 (fused E-pass): per block, load full u8 table to LDS once; stream
// pidx/pnode as int4 (non-temporal: streamed once, keep L2 for rtab/r8/start);
// boundary-scatter start[]; LDS-gather r -> u8 r8_all.
// prev boundary value comes from __shfl_up instead of a re-load (except lane 0).
__global__ __launch_bounds__(EB) void epass_kernel(const int* __restrict__ pidx,
                                                   const int* __restrict__ pnode,
                                                   const unsigned int* __restrict__ rtab_q,
                                                   int* __restrict__ start,
                                                   unsigned char* __restrict__ r8_all) {
    __shared__ unsigned int tab[TAB_U32];   // 100 KB
    const unsigned char* tabb = (const unsigned char*)tab;
    int tid = threadIdx.x;
    for (int i = tid; i < TAB_U32; i += EB) tab[i] = rtab_q[i];
    __syncthreads();

    int base_q = blockIdx.x * EB * EPT;
#pragma unroll
    for (int g = 0; g < EPT; g++) {
        int q = base_q + g * EB + tid;
        if (q >= NW_TOT) break;
        int e = q * 4;
        v4i v = __builtin_nontemporal_load((const v4i*)pidx + q);
        v4i w = __builtin_nontemporal_load((const v4i*)pnode + q);
        uchar4 r;
        r.x = tabb[w.x];
        r.y = tabb[w.y];
        r.z = tabb[w.z];
        r.w = tabb[w.w];
        ((uchar4*)r8_all)[q] = r;
        // pidx[e-1] is lane tid-1's v.w (q is lane-contiguous); only lane 0
        // of each wave needs the global re-load.
        int prev = __shfl_up((int)v.w, 1);
        if ((tid & 63) == 0) prev = (e == 0) ? -1 : pidx[e - 1];
        put_bounds(prev, v.x, e,     start);
        put_bounds(v.x,  v.y, e + 1, start);
        put_bounds(v.y,  v.z, e + 2, start);
        put_bounds(v.z,  v.w, e + 3, start);
        if (e + 4 == E_TOT) {
            for (int p = v.w + 1; p <= N_PATHS; ++p) start[p] = E_TOT;
        }
    }
}

// One quad of the segment product via elementary symmetric polynomials:
// (1-ra w)(1-rb w)(1-rc w)(1-rd w) = 1 - e1 w + e2 w^2 - e3 w^3 + e4 w^4,
// w = e^{-i 2pi f/16}. Bytes beyond the segment are masked via rem.
__device__ __forceinline__ void quad_step(unsigned grp, int rem,
                                          float& d0, float& d8,
                                          float dr[7], float di[7]) {
    float ra = fmaf((float)(grp & 255u), DEQ, RMIN);
    float rb = (rem > 1) ? fmaf((float)((grp >> 8) & 255u), DEQ, RMIN) : 0.0f;
    float rc = (rem > 2) ? fmaf((float)((grp >> 16) & 255u), DEQ, RMIN) : 0.0f;
    float rd = (rem > 3) ? fmaf((float)(grp >> 24), DEQ, RMIN) : 0.0f;
    float sab = ra + rb, qab = ra * rb;
    float scd = rc + rd, qcd = rc * rd;
    float e1 = sab + scd;
    float e2 = fmaf(sab, scd, qab + qcd);
    float e3 = fmaf(qab, scd, qcd * sab);
    float e4 = qab * qcd;
#pragma unroll
    for (int f = 1; f <= 7; f++) {
        float tr = fmaf(-e1, COS16[f], 1.0f);
        tr = fmaf( e2, COS16[(2 * f) & 15], tr);
        tr = fmaf(-e3, COS16[(3 * f) & 15], tr);
        tr = fmaf( e4, COS16[(4 * f) & 15], tr);
        float ti = e1 * SIN16[f];
        ti = fmaf(-e2, SIN16[(2 * f) & 15], ti);
        ti = fmaf( e3, SIN16[(3 * f) & 15], ti);
        ti = fmaf(-e4, SIN16[(4 * f) & 15], ti);
        float a = dr[f - 1], b = di[f - 1];
        dr[f - 1] = fmaf(a, tr, -b * ti);
        di[f - 1] = fmaf(a, ti,  b * tr);
    }
    d0 *= ((1.0f - e1) + (e2 - e3)) + e4;   // w = +1
    d8 *= ((1.0f + e1) + (e2 + e3)) + e4;   // w = -1
}

// Stage 3: one thread per path, barrier-free. De-serialized segment read:
// KW independent clamped word loads (one waitcnt) instead of a loop-carried
// load chain; compile-time-indexed unrolled quad loop. Garbage bytes beyond
// the segment are masked by rem logic; clamp keeps addresses in-bounds and
// the over-read coalesces with neighboring lanes' segments.
__global__ __launch_bounds__(PB) void path_kernel(const int* __restrict__ start,
                                                  const unsigned int* __restrict__ r8w,
                                                  float* __restrict__ out) {
    int p = blockIdx.x * PB + threadIdx.x;
    if (p >= N_PATHS) return;

    int s0 = start[p];
    int s1 = start[p + 1];
    int len = s1 - s0;
    int nq = (len + 3) >> 2;
    int a0 = s0 >> 2;
    unsigned sh = (unsigned)(s0 & 3) * 8u;

    unsigned wv[KW];
#pragma unroll
    for (int i = 0; i < KW; ++i) {
        int idx = a0 + i;
        wv[i] = r8w[idx < NW_TOT ? idx : (NW_TOT - 1)];
    }

    float d0 = 1.0f, d8 = 1.0f;
    float dr[7], di[7];
#pragma unroll
    for (int f = 0; f < 7; f++) { dr[f] = 1.0f; di[f] = 0.0f; }

#pragma unroll
    for (int q = 0; q < KW - 1; ++q) {
        if (q < nq) {
            unsigned grp = (unsigned)((((unsigned long long)wv[q + 1] << 32) |
                                       (unsigned long long)wv[q]) >> sh);
            quad_step(grp, len - 4 * q, d0, d8, dr, di);
        }
    }
    if (nq > KW - 1) {                       // len > 32: astronomically rare
        unsigned cur = wv[KW - 1];
        for (int q = KW - 1; q < nq; ++q) {
            int w = a0 + q + 1;
            unsigned nxt = (w < NW_TOT) ? r8w[w] : 0u;
            unsigned grp = (unsigned)((((unsigned long long)nxt << 32) |
                                       (unsigned long long)cur) >> sh);
            cur = nxt;
            quad_step(grp, len - 4 * q, d0, d8, dr, di);
        }
    }

    // H(f) = d0 * conj(D(f)) / |D(f)|^2; H(0)=1, |H(f)| <= 1.
    float Xr[8], Xi[8];
    Xr[0] = 1.0f; Xi[0] = 0.0f;
#pragma unroll
    for (int f = 1; f < 8; f++) {
        float a = dr[f - 1], b = di[f - 1];
        float m = fmaf(a, a, b * b);
        float inv = d0 * __builtin_amdgcn_rcpf(m);
        Xr[f] =  a * inv;
        Xi[f] = -b * inv;
    }
    float X8 = d0 * __builtin_amdgcn_rcpf(d8);

    // irfft n=16 exploiting t <-> 16-t symmetry:
    // x[t]    = (X0 + (-1)^t X8 + C_t - S_t)/16
    // x[16-t] = (X0 + (-1)^t X8 + C_t + S_t)/16
    float xt[16];
    float c0 = 0.0f, c8 = 0.0f;
#pragma unroll
    for (int f = 1; f < 8; f++) {
        c0 += 2.0f * Xr[f];
        c8 += (f & 1) ? -2.0f * Xr[f] : 2.0f * Xr[f];
    }
    xt[0] = fmaxf((Xr[0] + X8 + c0) * (1.0f / 16.0f), 0.0f);
    xt[8] = fmaxf((Xr[0] + X8 + c8) * (1.0f / 16.0f), 0.0f);
    float ssum = xt[0] + xt[8];
#pragma unroll
    for (int t = 1; t < 8; t++) {
        float Ct = 0.0f, St = 0.0f;
#pragma unroll
        for (int f = 1; f < 8; f++) {
            int kk = (f * t) & 15;
            Ct = fmaf(2.0f * Xr[f], COS16[kk], Ct);
            St = fmaf(2.0f * Xi[f], SIN16[kk], St);
        }
        float base = Xr[0] + ((t & 1) ? -X8 : X8) + Ct;
        float xa = fmaxf((base - St) * (1.0f / 16.0f), 0.0f);
        float xb = fmaxf((base + St) * (1.0f / 16.0f), 0.0f);
        xt[t] = xa;
        xt[16 - t] = xb;
        ssum += xa + xb;
    }

    float invs = __builtin_amdgcn_rcpf(ssum);
    v4f* op4 = (v4f*)(out + (size_t)p * 16);
    v4f t0 = { xt[15] * invs, xt[14] * invs, xt[13] * invs, xt[12] * invs };
    v4f t1 = { xt[11] * invs, xt[10] * invs, xt[9]  * invs, xt[8]  * invs };
    v4f t2 = { xt[7]  * invs, xt[6]  * invs, xt[5]  * invs, xt[4]  * invs };
    v4f t3 = { xt[3]  * invs, xt[2]  * invs, xt[1]  * invs, xt[0]  * invs };
    __builtin_nontemporal_store(t0, op4 + 0);   // out never re-read: keep L2
    __builtin_nontemporal_store(t1, op4 + 1);
    __builtin_nontemporal_store(t2, op4 + 2);
    __builtin_nontemporal_store(t3, op4 + 3);
}

extern "C" void kernel_launch(void* const* d_in, const int* in_sizes, int n_in,
                              void* d_out, int out_size, void* d_ws, size_t ws_size,
                              hipStream_t stream) {
    const float* params = (const float*)d_in[0];
    const int* path_idxs = (const int*)d_in[1];
    const int* path_nodes = (const int*)d_in[2];
    float* out = (float*)d_out;

    // workspace: rtab_q (100 KB) | start ((N_PATHS+1)*4) | r8_all (8 MB)
    size_t off_rq    = 0;
    size_t off_start = (off_rq + (size_t)N_NODES + 1023) & ~(size_t)1023;
    size_t off_r8    = (off_start + (size_t)(N_PATHS + 1) * 4 + 1023) & ~(size_t)1023;

    unsigned char* rtab_q = (unsigned char*)d_ws + off_rq;
    int* start = (int*)((char*)d_ws + off_start);
    unsigned char* r8_all = (unsigned char*)d_ws + off_r8;

    {
        int threads = 256;
        int blocks = (N_NODES + threads - 1) / threads;
        node_rq_kernel<<<blocks, threads, 0, stream>>>(params, rtab_q);
    }
    {
        int per_block = EB * EPT;                 // int4 groups per block
        int blocks = (NW_TOT + per_block - 1) / per_block;   // 245 = ~1/CU
        epass_kernel<<<blocks, EB, 0, stream>>>(path_idxs, path_nodes,
                                                (const unsigned int*)rtab_q,
                                                start, r8_all);
    }
    {
        int blocks = (N_PATHS + PB - 1) / PB;
        path_kernel<<<blocks, PB, 0, stream>>>(start, (const unsigned int*)r8_all, out);
    }
}

// Round 2
// 142.713 us; speedup vs baseline: 1.1724x; 1.1724x over previous
//
#include <hip/hip_runtime.h>
#include <math.h>

#define N_NODES  100000
#define N_PATHS  1000000
#define E_TOT    8000000
#define NW_TOT   (E_TOT / 4)    // r8 words
#define NF       9              // rfft bins for n=16
#define TAB_U32  25000          // 100000 bytes as u32
#define EB       1024           // epass threads
#define EPT      8              // int4 groups per epass thread (245 blocks = ~1/CU)
#define PB       256            // path_kernel threads
#define KW       9              // preloaded r8 words per path: covers len <= 32

// r quantization range: r = exp(-1/(p+0.5)), p in [0,1)
#define RMIN 0.135330f
#define RMAX 0.513420f
#define QSCALE (255.0f / (RMAX - RMIN))
#define DEQ    ((RMAX - RMIN) / 255.0f)

typedef int   v4i __attribute__((ext_vector_type(4)));
typedef float v4f __attribute__((ext_vector_type(4)));

// cos/sin(2*pi*k/16)
__device__ __constant__ float COS16[16] = {
  1.0f,  0.92387953f,  0.70710678f,  0.38268343f,  0.0f, -0.38268343f, -0.70710678f, -0.92387953f,
 -1.0f, -0.92387953f, -0.70710678f, -0.38268343f,  0.0f,  0.38268343f,  0.70710678f,  0.92387953f };
__device__ __constant__ float SIN16[16] = {
  0.0f,  0.38268343f,  0.70710678f,  0.92387953f,  1.0f,  0.92387953f,  0.70710678f,  0.38268343f,
  0.0f, -0.38268343f, -0.70710678f, -0.92387953f, -1.0f, -0.92387953f, -0.70710678f, -0.38268343f };

// Stage 1: quantized node table. r[n] = exp(-1/(params[n]+0.5)) -> u8.
// rfft16 of x[t]=r^t/k is A/(1 - r e^{-i w_f}); positive real A cancels
// under relu+normalize, so r alone captures the node.
__global__ void node_rq_kernel(const float* __restrict__ params,
                               unsigned char* __restrict__ rtab_q) {
    int n = blockIdx.x * blockDim.x + threadIdx.x;
    if (n >= N_NODES) return;
    float k = params[n] + 0.5f;
    float r = expf(-1.0f / k);
    float q = (r - RMIN) * QSCALE;
    q = fminf(fmaxf(q + 0.5f, 0.0f), 255.0f);
    rtab_q[n] = (unsigned char)q;
}

__device__ __forceinline__ void put_bounds(int a, int b, int e, int* __restrict__ start) {
    for (int p = a + 1; p <= b; ++p) start[p] = e;
}

// Stage 2 (fused E-pass): per block, load full u8 table to LDS once; stream
// pidx/pnode as int4 (REGULAR cached loads: the lane-0 boundary re-read below
// needs pidx lines to stay in L2 — NT loads here cost ~900cy stalls);
// boundary-scatter start[]; LDS-gather r -> u8 r8_all.
// prev boundary value comes from __shfl_up instead of a re-load (except lane 0).
__global__ __launch_bounds__(EB) void epass_kernel(const int* __restrict__ pidx,
                                                   const int* __restrict__ pnode,
                                                   const unsigned int* __restrict__ rtab_q,
                                                   int* __restrict__ start,
                                                   unsigned char* __restrict__ r8_all) {
    __shared__ unsigned int tab[TAB_U32];   // 100 KB
    const unsigned char* tabb = (const unsigned char*)tab;
    int tid = threadIdx.x;
    for (int i = tid; i < TAB_U32; i += EB) tab[i] = rtab_q[i];
    __syncthreads();

    int base_q = blockIdx.x * EB * EPT;
#pragma unroll
    for (int g = 0; g < EPT; g++) {
        int q = base_q + g * EB + tid;
        if (q >= NW_TOT) break;
        int e = q * 4;
        v4i v = *((const v4i*)pidx + q);
        v4i w = *((const v4i*)pnode + q);
        uchar4 r;
        r.x = tabb[w.x];
        r.y = tabb[w.y];
        r.z = tabb[w.z];
        r.w = tabb[w.w];
        ((uchar4*)r8_all)[q] = r;
        // pidx[e-1] is lane tid-1's v.w (q is lane-contiguous); only lane 0
        // of each wave needs the re-load, and it's an L2 hit (cached loads).
        int prev = __shfl_up((int)v.w, 1);
        if ((tid & 63) == 0) prev = (e == 0) ? -1 : pidx[e - 1];
        put_bounds(prev, v.x, e,     start);
        put_bounds(v.x,  v.y, e + 1, start);
        put_bounds(v.y,  v.z, e + 2, start);
        put_bounds(v.z,  v.w, e + 3, start);
        if (e + 4 == E_TOT) {
            for (int p = v.w + 1; p <= N_PATHS; ++p) start[p] = E_TOT;
        }
    }
}

// One quad of the segment product via elementary symmetric polynomials:
// (1-ra w)(1-rb w)(1-rc w)(1-rd w) = 1 - e1 w + e2 w^2 - e3 w^3 + e4 w^4,
// w = e^{-i 2pi f/16}. Bytes beyond the segment are masked via rem.
__device__ __forceinline__ void quad_step(unsigned grp, int rem,
                                          float& d0, float& d8,
                                          float dr[7], float di[7]) {
    float ra = fmaf((float)(grp & 255u), DEQ, RMIN);
    float rb = (rem > 1) ? fmaf((float)((grp >> 8) & 255u), DEQ, RMIN) : 0.0f;
    float rc = (rem > 2) ? fmaf((float)((grp >> 16) & 255u), DEQ, RMIN) : 0.0f;
    float rd = (rem > 3) ? fmaf((float)(grp >> 24), DEQ, RMIN) : 0.0f;
    float sab = ra + rb, qab = ra * rb;
    float scd = rc + rd, qcd = rc * rd;
    float e1 = sab + scd;
    float e2 = fmaf(sab, scd, qab + qcd);
    float e3 = fmaf(qab, scd, qcd * sab);
    float e4 = qab * qcd;
#pragma unroll
    for (int f = 1; f <= 7; f++) {
        float tr = fmaf(-e1, COS16[f], 1.0f);
        tr = fmaf( e2, COS16[(2 * f) & 15], tr);
        tr = fmaf(-e3, COS16[(3 * f) & 15], tr);
        tr = fmaf( e4, COS16[(4 * f) & 15], tr);
        float ti = e1 * SIN16[f];
        ti = fmaf(-e2, SIN16[(2 * f) & 15], ti);
        ti = fmaf( e3, SIN16[(3 * f) & 15], ti);
        ti = fmaf(-e4, SIN16[(4 * f) & 15], ti);
        float a = dr[f - 1], b = di[f - 1];
        dr[f - 1] = fmaf(a, tr, -b * ti);
        di[f - 1] = fmaf(a, ti,  b * tr);
    }
    d0 *= ((1.0f - e1) + (e2 - e3)) + e4;   // w = +1
    d8 *= ((1.0f + e1) + (e2 + e3)) + e4;   // w = -1
}

// Stage 3: one thread per path, barrier-free. De-serialized segment read:
// KW independent clamped word loads (one waitcnt) instead of a loop-carried
// load chain; compile-time-indexed unrolled quad loop. Output via REGULAR
// cached float4 stores: each lane writes 4x16B partials of its own 64B line;
// L2 write-allocate merges them into full-line evictions (NT stores streamed
// the partials unmerged -> 1.8x write amplification, round-1 counters).
__global__ __launch_bounds__(PB) void path_kernel(const int* __restrict__ start,
                                                  const unsigned int* __restrict__ r8w,
                                                  float* __restrict__ out) {
    int p = blockIdx.x * PB + threadIdx.x;
    if (p >= N_PATHS) return;

    int s0 = start[p];
    int s1 = start[p + 1];
    int len = s1 - s0;
    int nq = (len + 3) >> 2;
    int a0 = s0 >> 2;
    unsigned sh = (unsigned)(s0 & 3) * 8u;

    unsigned wv[KW];
#pragma unroll
    for (int i = 0; i < KW; ++i) {
        int idx = a0 + i;
        wv[i] = r8w[idx < NW_TOT ? idx : (NW_TOT - 1)];
    }

    float d0 = 1.0f, d8 = 1.0f;
    float dr[7], di[7];
#pragma unroll
    for (int f = 0; f < 7; f++) { dr[f] = 1.0f; di[f] = 0.0f; }

#pragma unroll
    for (int q = 0; q < KW - 1; ++q) {
        if (q < nq) {
            unsigned grp = (unsigned)((((unsigned long long)wv[q + 1] << 32) |
                                       (unsigned long long)wv[q]) >> sh);
            quad_step(grp, len - 4 * q, d0, d8, dr, di);
        }
    }
    if (nq > KW - 1) {                       // len > 32: astronomically rare
        unsigned cur = wv[KW - 1];
        for (int q = KW - 1; q < nq; ++q) {
            int w = a0 + q + 1;
            unsigned nxt = (w < NW_TOT) ? r8w[w] : 0u;
            unsigned grp = (unsigned)((((unsigned long long)nxt << 32) |
                                       (unsigned long long)cur) >> sh);
            cur = nxt;
            quad_step(grp, len - 4 * q, d0, d8, dr, di);
        }
    }

    // H(f) = d0 * conj(D(f)) / |D(f)|^2; H(0)=1, |H(f)| <= 1.
    float Xr[8], Xi[8];
    Xr[0] = 1.0f; Xi[0] = 0.0f;
#pragma unroll
    for (int f = 1; f < 8; f++) {
        float a = dr[f - 1], b = di[f - 1];
        float m = fmaf(a, a, b * b);
        float inv = d0 * __builtin_amdgcn_rcpf(m);
        Xr[f] =  a * inv;
        Xi[f] = -b * inv;
    }
    float X8 = d0 * __builtin_amdgcn_rcpf(d8);

    // irfft n=16 exploiting t <-> 16-t symmetry:
    // x[t]    = (X0 + (-1)^t X8 + C_t - S_t)/16
    // x[16-t] = (X0 + (-1)^t X8 + C_t + S_t)/16
    float xt[16];
    float c0 = 0.0f, c8 = 0.0f;
#pragma unroll
    for (int f = 1; f < 8; f++) {
        c0 += 2.0f * Xr[f];
        c8 += (f & 1) ? -2.0f * Xr[f] : 2.0f * Xr[f];
    }
    xt[0] = fmaxf((Xr[0] + X8 + c0) * (1.0f / 16.0f), 0.0f);
    xt[8] = fmaxf((Xr[0] + X8 + c8) * (1.0f / 16.0f), 0.0f);
    float ssum = xt[0] + xt[8];
#pragma unroll
    for (int t = 1; t < 8; t++) {
        float Ct = 0.0f, St = 0.0f;
#pragma unroll
        for (int f = 1; f < 8; f++) {
            int kk = (f * t) & 15;
            Ct = fmaf(2.0f * Xr[f], COS16[kk], Ct);
            St = fmaf(2.0f * Xi[f], SIN16[kk], St);
        }
        float base = Xr[0] + ((t & 1) ? -X8 : X8) + Ct;
        float xa = fmaxf((base - St) * (1.0f / 16.0f), 0.0f);
        float xb = fmaxf((base + St) * (1.0f / 16.0f), 0.0f);
        xt[t] = xa;
        xt[16 - t] = xb;
        ssum += xa + xb;
    }

    float invs = __builtin_amdgcn_rcpf(ssum);
    v4f* op4 = (v4f*)(out + (size_t)p * 16);
    op4[0] = (v4f){ xt[15] * invs, xt[14] * invs, xt[13] * invs, xt[12] * invs };
    op4[1] = (v4f){ xt[11] * invs, xt[10] * invs, xt[9]  * invs, xt[8]  * invs };
    op4[2] = (v4f){ xt[7]  * invs, xt[6]  * invs, xt[5]  * invs, xt[4]  * invs };
    op4[3] = (v4f){ xt[3]  * invs, xt[2]  * invs, xt[1]  * invs, xt[0]  * invs };
}

extern "C" void kernel_launch(void* const* d_in, const int* in_sizes, int n_in,
                              void* d_out, int out_size, void* d_ws, size_t ws_size,
                              hipStream_t stream) {
    const float* params = (const float*)d_in[0];
    const int* path_idxs = (const int*)d_in[1];
    const int* path_nodes = (const int*)d_in[2];
    float* out = (float*)d_out;

    // workspace: rtab_q (100 KB) | start ((N_PATHS+1)*4) | r8_all (8 MB)
    size_t off_rq    = 0;
    size_t off_start = (off_rq + (size_t)N_NODES + 1023) & ~(size_t)1023;
    size_t off_r8    = (off_start + (size_t)(N_PATHS + 1) * 4 + 1023) & ~(size_t)1023;

    unsigned char* rtab_q = (unsigned char*)d_ws + off_rq;
    int* start = (int*)((char*)d_ws + off_start);
    unsigned char* r8_all = (unsigned char*)d_ws + off_r8;

    {
        int threads = 256;
        int blocks = (N_NODES + threads - 1) / threads;
        node_rq_kernel<<<blocks, threads, 0, stream>>>(params, rtab_q);
    }
    {
        int per_block = EB * EPT;                 // int4 groups per block
        int blocks = (NW_TOT + per_block - 1) / per_block;   // 245 = ~1/CU
        epass_kernel<<<blocks, EB, 0, stream>>>(path_idxs, path_nodes,
                                                (const unsigned int*)rtab_q,
                                                start, r8_all);
    }
    {
        int blocks = (N_PATHS + PB - 1) / PB;
        path_kernel<<<blocks, PB, 0, stream>>>(start, (const unsigned int*)r8_all, out);
    }
}